// Round 2
// baseline (17.381 us; speedup 1.0000x reference)
//
#include <hip/hip_runtime.h>

// Problem constants (from reference)
#define PS 16           // patch size
#define DR 32           // dst patch rows
#define DC 32           // dst patch cols
#define MULT 2
#define SR (DR * MULT)  // 64
#define SC (DC * MULT)  // 64
#define NB 8            // batch
#define NS 2            // num source images
#define DP (DR * DC)    // 1024 dst patches
#define SP (SR * SC)    // 4096 src patches

// src_images: [NS, NB, 3, 1024, 1024] f32 -> rows of 256 float4
// out:        [NB, 3, 512, 512]       f32 -> rows of 128 float4
//
// Block = 256 threads handles 4 consecutive flat patches (g0..g0+3).
// Since dst_patch_idx is an aligned arange, those 4 patches share dprow and
// have consecutive dpcol aligned to 4 -> for each patch row r, the 16 threads
// {r*16 .. r*16+15} write one CONTIGUOUS aligned 256 B span (2 full 128 B
// lines per store instruction). Reads stay 64 B-granular per 4-lane group
// (the max contiguity the gather layout admits).
__global__ __launch_bounds__(256) void MultiViTPatchMapper_kernel(
    const float4* __restrict__ src,
    const int* __restrict__ img_idx,
    const int* __restrict__ sp_idx,
    const int* __restrict__ dp_idx,
    float4* __restrict__ out) {
    const int g0  = blockIdx.x * 4;          // first flat (b, j) patch of block
    const int tid = threadIdx.x;
    const int r   = tid >> 4;                // patch row 0..15
    const int k   = tid & 15;                // position within row-group
    const int p   = k >> 2;                  // which of the 4 patches, 0..3
    const int q   = k & 3;                   // float4 within 64 B patch row

    const int g = g0 + p;                    // flat patch id 0..8191
    const int b = g >> 10;                   // / DP

    const int img = img_idx[g];
    const int sp  = sp_idx[g];
    const int dp  = dp_idx[g];

    const int sprow = sp >> 6;               // / SC
    const int spcol = sp & 63;               // % SC
    const int dprow = dp >> 5;               // / DC
    const int dpcol = dp & 31;               // % DC

    // float4 row widths: src row = 256 float4, out row = 128 float4
    const int src_plane0 = ((img * NB + b) * 3) * (SR * PS);   // row index base
    const int out_plane0 = (b * 3) * (DR * PS);

    const int srow = sprow * PS + r;
    const int drow = dprow * PS + r;
    const int scol = spcol * 4 + q;
    const int dcol = dpcol * 4 + q;

#pragma unroll
    for (int c = 0; c < 3; ++c) {
        const int si = (src_plane0 + c * (SR * PS) + srow) * (SC * PS / 4) + scol;
        const int di = (out_plane0 + c * (DR * PS) + drow) * (DC * PS / 4) + dcol;
        out[di] = src[si];
    }
}

extern "C" void kernel_launch(void* const* d_in, const int* in_sizes, int n_in,
                              void* d_out, int out_size, void* d_ws, size_t ws_size,
                              hipStream_t stream) {
    const float* src     = (const float*)d_in[0];   // [NS, NB, 3, 1024, 1024]
    const int*   img_idx = (const int*)d_in[1];     // [NB, DP]
    const int*   sp_idx  = (const int*)d_in[2];     // [NB, DP]
    const int*   dp_idx  = (const int*)d_in[3];     // [NB, DP]
    float*       out     = (float*)d_out;           // [NB, 3, 512, 512]

    const int total_patches = NB * DP;              // 8192
    const int blocks = total_patches / 4;           // 2048 blocks x 256 threads

    MultiViTPatchMapper_kernel<<<blocks, 256, 0, stream>>>(
        (const float4*)src, img_idx, sp_idx, dp_idx, (float4*)out);
}

// Round 3
// 17.107 us; speedup vs baseline: 1.0160x; 1.0160x over previous
//
#include <hip/hip_runtime.h>

// Problem constants (from reference)
#define PS 16           // patch size
#define DR 32           // dst patch rows
#define DC 32           // dst patch cols
#define MULT 2
#define SR (DR * MULT)  // 64
#define SC (DC * MULT)  // 64
#define NB 8            // batch
#define NS 2            // num source images
#define DP (DR * DC)    // 1024 dst patches
#define SP (SR * SC)    // 4096 src patches

// src_images: [NS, NB, 3, 1024, 1024] f32 -> rows of 256 float4
// out:        [NB, 3, 512, 512]       f32 -> rows of 128 float4
//
// Block = 256 threads handles 8 consecutive flat patches (two quads).
// For each quad, thread (r = tid>>4, k = tid&15, p = k>>2, q = k&3) moves one
// float4 per channel; 16 threads per patch-row write one contiguous aligned
// 256 B span. Both quads' index loads are issued first (two independent
// dependency chains), then all 6 data loads, then all 6 stores -> deeper MLP
// per wave to cover the two-hop (idx -> data) cold-miss latency.
__global__ __launch_bounds__(256) void MultiViTPatchMapper_kernel(
    const float4* __restrict__ src,
    const int* __restrict__ img_idx,
    const int* __restrict__ sp_idx,
    const int* __restrict__ dp_idx,
    float4* __restrict__ out) {
    const int g0  = blockIdx.x * 8;
    const int tid = threadIdx.x;
    const int r   = tid >> 4;                // patch row 0..15
    const int k   = tid & 15;
    const int p   = k >> 2;                  // patch within quad
    const int q   = k & 3;                   // float4 within 64 B patch row

    const int g[2] = { g0 + p, g0 + 4 + p };

    int img[2], sp[2], dp[2];
#pragma unroll
    for (int u = 0; u < 2; ++u) {            // issue all 6 idx loads up front
        img[u] = img_idx[g[u]];
        sp[u]  = sp_idx[g[u]];
        dp[u]  = dp_idx[g[u]];
    }

    float4 v[2][3];
    int    di[2][3];
#pragma unroll
    for (int u = 0; u < 2; ++u) {
        const int b     = g[u] >> 10;        // / DP
        const int sprow = sp[u] >> 6;
        const int spcol = sp[u] & 63;
        const int dprow = dp[u] >> 5;
        const int dpcol = dp[u] & 31;

        const int srow = sprow * PS + r;
        const int drow = dprow * PS + r;
        const int scol = spcol * 4 + q;
        const int dcol = dpcol * 4 + q;

        const int sbase = ((img[u] * NB + b) * 3) * (SR * PS);  // row index base
        const int obase = (b * 3) * (DR * PS);

#pragma unroll
        for (int c = 0; c < 3; ++c) {        // issue all data loads
            v[u][c]  = src[(sbase + c * (SR * PS) + srow) * (SC * PS / 4) + scol];
            di[u][c] = (obase + c * (DR * PS) + drow) * (DC * PS / 4) + dcol;
        }
    }

#pragma unroll
    for (int u = 0; u < 2; ++u)
#pragma unroll
        for (int c = 0; c < 3; ++c)
            out[di[u][c]] = v[u][c];
}

extern "C" void kernel_launch(void* const* d_in, const int* in_sizes, int n_in,
                              void* d_out, int out_size, void* d_ws, size_t ws_size,
                              hipStream_t stream) {
    const float* src     = (const float*)d_in[0];   // [NS, NB, 3, 1024, 1024]
    const int*   img_idx = (const int*)d_in[1];     // [NB, DP]
    const int*   sp_idx  = (const int*)d_in[2];     // [NB, DP]
    const int*   dp_idx  = (const int*)d_in[3];     // [NB, DP]
    float*       out     = (float*)d_out;           // [NB, 3, 512, 512]

    const int total_patches = NB * DP;              // 8192
    const int blocks = total_patches / 8;           // 1024 blocks x 256 threads

    MultiViTPatchMapper_kernel<<<blocks, 256, 0, stream>>>(
        (const float4*)src, img_idx, sp_idx, dp_idx, (float4*)out);
}